// Round 14
// baseline (469.333 us; speedup 1.0000x reference)
//
#include <hip/hip_runtime.h>
#include <hip/hip_bf16.h>

#define NT 6
#define BM 256
#define BN 256
#define BK 64
#define SLOT_S 16384      // shorts per A-slot: 256 rows x 64 = 32KB
#define AH1 8192          // rows 128-255

typedef __attribute__((ext_vector_type(4))) float f32x4;
typedef __attribute__((ext_vector_type(8))) short bf16x8;

__device__ __forceinline__ short f2bf(float f) {
    __hip_bfloat16 h = __float2bfloat16(f);
    return (short)__builtin_bit_cast(unsigned short, h);
}

// ---- 1. segment argmax: packed (conf_bits<<32) | ~idx, atomicMax ----
__global__ void k_segmax(const float* __restrict__ conf,
                         const int* __restrict__ bidx,
                         unsigned long long* __restrict__ packed, int E) {
    int i = blockIdx.x * blockDim.x + threadIdx.x;
    if (i >= E) return;
    unsigned cb = __float_as_uint(conf[i]);
    unsigned long long p = ((unsigned long long)cb << 32) | (unsigned)(~(unsigned)i);
    atomicMax(&packed[bidx[i]], p);
}

// ---- 2. base[t][n] = emb[t] . W1[n,:d4] + b1[n]; extract conf/x/y columns ----
__global__ void k_base(const float* __restrict__ emb, const float* __restrict__ W1,
                       const float* __restrict__ b1, float* __restrict__ base,
                       float* __restrict__ vecs, int d2, int d4) {
    int gw = (blockIdx.x * blockDim.x + threadIdx.x) >> 6;
    int lane = threadIdx.x & 63;
    int t = gw / d2, n = gw % d2;
    const float* e = emb + (size_t)t * d4;
    const float* w = W1 + (size_t)n * (d4 + 3);
    float s = 0.f;
    for (int k = lane; k < d4; k += 64) s += e[k] * w[k];
#pragma unroll
    for (int m = 32; m; m >>= 1) s += __shfl_xor(s, m);
    if (lane == 0) {
        base[gw] = s + b1[n];
        if (t == 0) {
            vecs[n]          = w[d4];
            vecs[d2 + n]     = w[d4 + 1];
            vecs[2 * d2 + n] = w[d4 + 2];
        }
    }
}

// ---- 3. W2 fp32 -> bf16 ----
__global__ void k_w2cast(const float* __restrict__ W2, short* __restrict__ W2b, long n) {
    long i = ((long)blockIdx.x * blockDim.x + threadIdx.x) * 8;
    if (i >= n) return;
    bf16x8 v;
#pragma unroll
    for (int j = 0; j < 8; ++j) v[j] = f2bf(W2[i + j]);
    *(bf16x8*)(W2b + i) = v;
}

// ---- 4. h[b][n] = relu(base[t][n] + conf*cv[n] + lx*xv[n] + ly*yv[n]) -> bf16 ----
__global__ void k_h(const unsigned long long* __restrict__ packed,
                    const int* __restrict__ etype, const float* __restrict__ loc,
                    const float* __restrict__ base, const float* __restrict__ vecs,
                    float* __restrict__ mask, short* __restrict__ h, int d2) {
    int b = blockIdx.x;
    int tid = threadIdx.x;
    unsigned long long p = packed[b];
    bool has = (p != 0ULL);
    float conf = 0.f, lx = 0.f, ly = 0.f;
    int t = 0;
    if (has) {
        unsigned idx = ~(unsigned)(p & 0xFFFFFFFFu);
        conf = __uint_as_float((unsigned)(p >> 32));
        t  = etype[idx];
        lx = loc[2 * (size_t)idx]     * (1.0f / 640.0f);
        ly = loc[2 * (size_t)idx + 1] * (1.0f / 480.0f);
    }
    if (tid == 0) mask[b] = has ? 1.0f : 0.0f;
    const float* bs = base + (size_t)t * d2;
    const float* cv = vecs;
    const float* xv = vecs + d2;
    const float* yv = vecs + 2 * d2;
    int n0 = tid * 8;
    bf16x8 v;
#pragma unroll
    for (int j = 0; j < 8; ++j) {
        int n = n0 + j;
        float g = bs[n] + conf * cv[n] + lx * xv[n] + ly * yv[n];
        g = fmaxf(g, 0.f);
        v[j] = has ? f2bf(g) : (short)0;
    }
    *(bf16x8*)(h + (size_t)b * d2 + n0) = v;
}

// ---- 5. GEMM: R10 structure with DIRECT-GLOBAL B ----
// 256x256, BK=64, A-only LDS dbuf (2 x 32KB), 8 waves (2x4), 16x16x32 MFMA.
// Per K64 tile: {16 ds_read_b128 A-frags; 8 global_load_dwordx4 B-frags
// (W2 is L2/L3-hot: 16MB reused by 64 M-blocks); 4 GLL staging A(t+1);
// 64 MFMA one cluster; vmcnt(0); barrier}. Removing B from LDS cuts the
// LDS pipe 256KB -> 160KB per tile (~2800 -> ~1750 cyc) — the binding
// resource, since R3..R13 showed LDS and MFMA pipes run serially at every
// schedule. B-load latency hides under the 2400-cyc MFMA cluster.
// A swizzle (R9/R10-verified, 0 conflicts): LDS[r][p] = global chunk
// p^(r&7); GLL dest linear, source pre-inverse-swizzled.

#define GLL(src, dst) __builtin_amdgcn_global_load_lds(                      \
    (const __attribute__((address_space(1))) void*)(src),                    \
    (__attribute__((address_space(3))) void*)(dst), 16, 0, 0)

#define ST_AH0(ws, kt) { GLL(pA + (size_t)(kt) * 64, (ws) + dst1);           \
                         GLL(pA + (size_t)64 * K + (kt) * 64, (ws) + dst2); }
#define ST_AH1(ws, kt) { GLL(pA + (size_t)128 * K + (kt) * 64, (ws) + AH1 + dst1); \
                         GLL(pA + (size_t)192 * K + (kt) * 64, (ws) + AH1 + dst2); }

__global__ __launch_bounds__(512, 2)
void k_gemm(const short* __restrict__ A, const short* __restrict__ Bm,
            const float* __restrict__ b2, const float* __restrict__ mask,
            float* __restrict__ C, int M, int N, int K, int nbn) {
    __shared__ __align__(16) short lds[2 * SLOT_S];   // 64 KiB

    int tid = threadIdx.x;
    int lane = tid & 63;
    int wave = tid >> 6;            // 0..7
    int wr = wave >> 2, wc = wave & 3;

    // XCD-aware bijective swizzle (grid = 1024, % 8 == 0)
    int bid = blockIdx.x;
    int wg = (bid & 7) * ((int)gridDim.x >> 3) + (bid >> 3);
    int bm = wg / nbn, bn = wg % nbn;
    int row0 = bm * BM, col0 = bn * BN;

    // ---- A staging precompute (R10-verified) ----
    int r1 = tid >> 3;                         // 0..63
    int pg = tid & 7;
    int cg = pg ^ (r1 & 7);                    // inverse-swizzled source chunk
    const short* pA = A + (size_t)(row0 + r1) * K + cg * 8;
    int dst1 = tid * 8;
    int dst2 = 4096 + tid * 8;

    // ---- A fragment read offsets (R10-verified, 0 conflicts) ----
    int frow = lane & 15, fk = lane >> 4;
    int kx = frow & 7;
    int aoffs0 = (wr * 64 + frow) * 64 + ((fk) ^ kx) * 8;
    int aoffs1 = (wr * 64 + frow) * 64 + ((4 + fk) ^ kx) * 8;

    // ---- B direct-global per-lane base (rows col0 + (n>>1)*128 + wc*32 +
    //      (n&1)*16 + frow; chunk (ks*4+fk)*8 within the K64 tile) ----
    const short* pB0 = Bm + (size_t)(col0 + wc * 32 + frow) * K + fk * 8;
    const short* pB1 = pB0 + (size_t)16 * K;
    const short* pB2 = pB0 + (size_t)128 * K;
    const short* pB3 = pB0 + (size_t)144 * K;

    f32x4 acc[8][4] = {};
    bf16x8 aA[8][2], bB[4][2];

    int KT = K / BK;                           // 32

    // ---- prologue: stage A tile 0 into slot 0, drain once ----
    ST_AH0(lds, 0); ST_AH1(lds, 0);
    asm volatile("s_waitcnt vmcnt(0)" ::: "memory");
    __builtin_amdgcn_s_barrier();

#pragma unroll 1
    for (int t = 0; t < KT; ++t) {
        const short* sl = lds + (t & 1) * SLOT_S;
        short* wsl = lds + ((t + 1) & 1) * SLOT_S;
        size_t ko = (size_t)t * 64;

        // ---- 16 ds_read_b128: A fragments for the whole tile ----
#pragma unroll
        for (int m = 0; m < 4; ++m) {
            aA[m][0]     = *(const bf16x8*)(sl + aoffs0 + m * 1024);
            aA[m][1]     = *(const bf16x8*)(sl + aoffs1 + m * 1024);
        }
#pragma unroll
        for (int m = 0; m < 4; ++m) {
            aA[4 + m][0] = *(const bf16x8*)(sl + AH1 + aoffs0 + m * 1024);
            aA[4 + m][1] = *(const bf16x8*)(sl + AH1 + aoffs1 + m * 1024);
        }

        // ---- 8 direct-global B fragment loads (L2-hot W2) ----
#pragma unroll
        for (int ks = 0; ks < 2; ++ks) {
            bB[0][ks] = *(const bf16x8*)(pB0 + ko + ks * 32);
            bB[1][ks] = *(const bf16x8*)(pB1 + ko + ks * 32);
            bB[2][ks] = *(const bf16x8*)(pB2 + ko + ks * 32);
            bB[3][ks] = *(const bf16x8*)(pB3 + ko + ks * 32);
        }

        // ---- stage A tile t+1 (4 GLL) — lands under the MFMA cluster ----
        if (t < KT - 1) { ST_AH0(wsl, t + 1); ST_AH1(wsl, t + 1); }

        // ---- 64 MFMA, one cluster ----
        __builtin_amdgcn_s_setprio(1);
#pragma unroll
        for (int m = 0; m < 8; ++m)
#pragma unroll
            for (int n = 0; n < 4; ++n) {
                acc[m][n] = __builtin_amdgcn_mfma_f32_16x16x32_bf16(
                    aA[m][0], bB[n][0], acc[m][n], 0, 0, 0);
                acc[m][n] = __builtin_amdgcn_mfma_f32_16x16x32_bf16(
                    aA[m][1], bB[n][1], acc[m][n], 0, 0, 0);
            }
        __builtin_amdgcn_s_setprio(0);

        if (t < KT - 1) {
            asm volatile("s_waitcnt vmcnt(0)" ::: "memory");
            __builtin_amdgcn_s_barrier();
        }
    }

    // ---- epilogue: +b2, *mask (R10 mapping, verified) ----
#pragma unroll
    for (int mi = 0; mi < 8; ++mi) {
        int rbase = row0 + (mi >> 2) * 128 + wr * 64 + (mi & 3) * 16 + fk * 4;
#pragma unroll
        for (int j = 0; j < 4; ++j) {
            int r = rbase + j;
            float mk = mask[r];
#pragma unroll
            for (int ni = 0; ni < 4; ++ni) {
                int cc = col0 + (ni >> 1) * 128 + wc * 32 + (ni & 1) * 16 + frow;
                C[(size_t)r * N + cc] = (acc[mi][ni][j] + b2[cc]) * mk;
            }
        }
    }
}

extern "C" void kernel_launch(void* const* d_in, const int* in_sizes, int n_in,
                              void* d_out, int out_size, void* d_ws, size_t ws_size,
                              hipStream_t stream) {
    const int* etype   = (const int*)d_in[0];
    const float* conf  = (const float*)d_in[1];
    const float* loc   = (const float*)d_in[2];
    const int* bidx    = (const int*)d_in[3];
    const float* emb   = (const float*)d_in[5];
    const float* W1    = (const float*)d_in[6];
    const float* b1    = (const float*)d_in[7];
    const float* W2    = (const float*)d_in[8];
    const float* b2    = (const float*)d_in[9];
    float* out = (float*)d_out;

    int E  = in_sizes[0];
    int d2 = in_sizes[7];           // 2048
    int d  = in_sizes[9];           // 4096
    int d4 = in_sizes[5] / NT;      // 1024
    int B  = out_size / d;          // 16384

    char* ws = (char*)d_ws;
    unsigned long long* packed = (unsigned long long*)ws;     // B*8
    float* mask = (float*)(ws + (size_t)B * 8);               // B*4
    float* base = mask + B;                                   // NT*d2
    float* vecs = base + NT * d2;                             // 3*d2
    short* w2b  = (short*)(vecs + 3 * d2);                    // d*d2 bf16
    short* h    = w2b + (size_t)d * d2;                       // B*d2 bf16

    hipMemsetAsync(packed, 0, (size_t)B * 8, stream);
    k_segmax<<<(E + 255) / 256, 256, 0, stream>>>(conf, bidx, packed, E);
    k_base<<<(NT * d2) / 4, 256, 0, stream>>>(emb, W1, b1, base, vecs, d2, d4);
    long nw2 = (long)d * d2;
    k_w2cast<<<(int)(nw2 / 8 / 256), 256, 0, stream>>>(W2, w2b, nw2);
    k_h<<<B, 256, 0, stream>>>(packed, etype, loc, base, vecs, mask, h, d2);
    int nbm = B / BM, nbn = d / BN;
    k_gemm<<<dim3(nbm * nbn), dim3(512), 0, stream>>>(h, w2b, b2, mask, out, B, d, d2, nbn);
}

// Round 15
// 348.050 us; speedup vs baseline: 1.3485x; 1.3485x over previous
//
#include <hip/hip_runtime.h>
#include <hip/hip_bf16.h>

#define NT 6
#define BM 128
#define BN 128
#define BK 64
#define SLOT_S 16384      // shorts per dbuf slot: A 128x64 + B 128x64 = 32KB
#define BOFF 8192         // B offset within slot (shorts)

typedef __attribute__((ext_vector_type(4))) float f32x4;
typedef __attribute__((ext_vector_type(8))) short bf16x8;

__device__ __forceinline__ short f2bf(float f) {
    __hip_bfloat16 h = __float2bfloat16(f);
    return (short)__builtin_bit_cast(unsigned short, h);
}

// ---- 1. segment argmax: packed (conf_bits<<32) | ~idx, atomicMax ----
__global__ void k_segmax(const float* __restrict__ conf,
                         const int* __restrict__ bidx,
                         unsigned long long* __restrict__ packed, int E) {
    int i = blockIdx.x * blockDim.x + threadIdx.x;
    if (i >= E) return;
    unsigned cb = __float_as_uint(conf[i]);
    unsigned long long p = ((unsigned long long)cb << 32) | (unsigned)(~(unsigned)i);
    atomicMax(&packed[bidx[i]], p);
}

// ---- 2. base[t][n] = emb[t] . W1[n,:d4] + b1[n]; extract conf/x/y columns ----
__global__ void k_base(const float* __restrict__ emb, const float* __restrict__ W1,
                       const float* __restrict__ b1, float* __restrict__ base,
                       float* __restrict__ vecs, int d2, int d4) {
    int gw = (blockIdx.x * blockDim.x + threadIdx.x) >> 6;
    int lane = threadIdx.x & 63;
    int t = gw / d2, n = gw % d2;
    const float* e = emb + (size_t)t * d4;
    const float* w = W1 + (size_t)n * (d4 + 3);
    float s = 0.f;
    for (int k = lane; k < d4; k += 64) s += e[k] * w[k];
#pragma unroll
    for (int m = 32; m; m >>= 1) s += __shfl_xor(s, m);
    if (lane == 0) {
        base[gw] = s + b1[n];
        if (t == 0) {
            vecs[n]          = w[d4];
            vecs[d2 + n]     = w[d4 + 1];
            vecs[2 * d2 + n] = w[d4 + 2];
        }
    }
}

// ---- 3. W2 fp32 -> bf16 ----
__global__ void k_w2cast(const float* __restrict__ W2, short* __restrict__ W2b, long n) {
    long i = ((long)blockIdx.x * blockDim.x + threadIdx.x) * 8;
    if (i >= n) return;
    bf16x8 v;
#pragma unroll
    for (int j = 0; j < 8; ++j) v[j] = f2bf(W2[i + j]);
    *(bf16x8*)(W2b + i) = v;
}

// ---- 4. h[b][n] = relu(base[t][n] + conf*cv[n] + lx*xv[n] + ly*yv[n]) -> bf16 ----
__global__ void k_h(const unsigned long long* __restrict__ packed,
                    const int* __restrict__ etype, const float* __restrict__ loc,
                    const float* __restrict__ base, const float* __restrict__ vecs,
                    float* __restrict__ mask, short* __restrict__ h, int d2) {
    int b = blockIdx.x;
    int tid = threadIdx.x;
    unsigned long long p = packed[b];
    bool has = (p != 0ULL);
    float conf = 0.f, lx = 0.f, ly = 0.f;
    int t = 0;
    if (has) {
        unsigned idx = ~(unsigned)(p & 0xFFFFFFFFu);
        conf = __uint_as_float((unsigned)(p >> 32));
        t  = etype[idx];
        lx = loc[2 * (size_t)idx]     * (1.0f / 640.0f);
        ly = loc[2 * (size_t)idx + 1] * (1.0f / 480.0f);
    }
    if (tid == 0) mask[b] = has ? 1.0f : 0.0f;
    const float* bs = base + (size_t)t * d2;
    const float* cv = vecs;
    const float* xv = vecs + d2;
    const float* yv = vecs + 2 * d2;
    int n0 = tid * 8;
    bf16x8 v;
#pragma unroll
    for (int j = 0; j < 8; ++j) {
        int n = n0 + j;
        float g = bs[n] + conf * cv[n] + lx * xv[n] + ly * yv[n];
        g = fmaxf(g, 0.f);
        v[j] = has ? f2bf(g) : (short)0;
    }
    *(bf16x8*)(h + (size_t)b * d2 + n0) = v;
}

// ---- 5. GEMM: R10 mega-phase x 2 independent blocks per CU ----
// 128x128 tile, 4 waves (2x2, 64x64 each), BK=64, A+B dbuf = 64KB LDS
// -> 2 blocks/CU, each its own barrier domain. Each SIMD hosts one wave
// from EACH block; blocks drift anti-phase, so block0's LDS read-drain
// hides under block1's 32-MFMA cluster (m114 cross-wave overlap) — the
// mechanism 15 rounds of intra-block scheduling could not create.
// Per tile per wave: {16 ds_read_b128; 8 GLL stage(t+1); 32 MFMA one
// cluster; vmcnt(0); barrier} — R10's proven deep-queue structure.
// Swizzle (R10-family, 0-conflict): LDS phys chunk p of row r holds
// global chunk p^(r&7); GLL dest linear, source pre-inverse-swizzled;
// reads apply the same XOR. 128B rows -> every row bank-aligned; each
// 16-lane quarter covers all 32 banks exactly 2x (free).

#define GLL(src, dst) __builtin_amdgcn_global_load_lds(                      \
    (const __attribute__((address_space(1))) void*)(src),                    \
    (__attribute__((address_space(3))) void*)(dst), 16, 0, 0)

// 8 GLL: A rows r0+32i, B rows r0+32i (i=0..3); chunk cg constant (32i%8==0)
#define STAGE(ws, kt) do {                                                   \
    _Pragma("unroll") for (int i = 0; i < 4; ++i)                            \
        GLL(pA + (size_t)(kt) * 64 + (size_t)32 * i * K,                     \
            (ws) + dstA + i * 2048);                                         \
    _Pragma("unroll") for (int i = 0; i < 4; ++i)                            \
        GLL(pB + (size_t)(kt) * 64 + (size_t)32 * i * K,                     \
            (ws) + BOFF + dstA + i * 2048);                                  \
} while (0)

__global__ __launch_bounds__(256, 2)
void k_gemm(const short* __restrict__ A, const short* __restrict__ Bm,
            const float* __restrict__ b2, const float* __restrict__ mask,
            float* __restrict__ C, int M, int N, int K, int nbn) {
    __shared__ __align__(16) short lds[2 * SLOT_S];   // 64 KiB

    int tid = threadIdx.x;
    int lane = tid & 63;
    int wave = tid >> 6;            // 0..3
    int wr = wave >> 1, wc = wave & 1;

    // XCD-aware bijective swizzle (grid = 4096, % 8 == 0)
    int bid = blockIdx.x;
    int wg = (bid & 7) * ((int)gridDim.x >> 3) + (bid >> 3);
    int bm = wg / nbn, bn = wg % nbn;
    int row0 = bm * BM, col0 = bn * BN;

    // ---- staging precompute: thread covers granules tid + 256i ----
    int r0 = tid >> 3;                         // 0..31
    int pg = tid & 7;
    int cg = pg ^ (r0 & 7);                    // inverse-swizzled source chunk
    const short* pA = A + (size_t)(row0 + r0) * K + cg * 8;
    const short* pB = Bm + (size_t)(col0 + r0) * K + cg * 8;
    int dstA = tid * 8;                        // shorts; +i*2048 per granule

    // ---- fragment read offsets (R10-family, 0-conflict) ----
    int frow = lane & 15, fk = lane >> 4;
    int kx = frow & 7;
    int aoffs0 = (wr * 64 + frow) * 64 + ((fk) ^ kx) * 8;        // ks=0
    int aoffs1 = (wr * 64 + frow) * 64 + ((4 + fk) ^ kx) * 8;    // ks=1
    int boffs0 = BOFF + (wc * 64 + frow) * 64 + ((fk) ^ kx) * 8;
    int boffs1 = BOFF + (wc * 64 + frow) * 64 + ((4 + fk) ^ kx) * 8;

    f32x4 acc[4][4] = {};
    bf16x8 aA[4][2], bB[4][2];

    int KT = K / BK;                           // 32

    // ---- prologue: stage tile 0 into slot 0, drain once ----
    STAGE(lds, 0);
    asm volatile("s_waitcnt vmcnt(0)" ::: "memory");
    __builtin_amdgcn_s_barrier();

#pragma unroll 1
    for (int t = 0; t < KT; ++t) {
        const short* sl = lds + (t & 1) * SLOT_S;
        short* wsl = lds + ((t + 1) & 1) * SLOT_S;

        // ---- 16 ds_read_b128: whole tile's fragments ----
#pragma unroll
        for (int m = 0; m < 4; ++m) {
            aA[m][0] = *(const bf16x8*)(sl + aoffs0 + m * 1024);
            aA[m][1] = *(const bf16x8*)(sl + aoffs1 + m * 1024);
        }
#pragma unroll
        for (int n = 0; n < 4; ++n) {
            bB[n][0] = *(const bf16x8*)(sl + boffs0 + n * 1024);
            bB[n][1] = *(const bf16x8*)(sl + boffs1 + n * 1024);
        }

        // ---- stage tile t+1 (8 GLL) — lands under the MFMA cluster ----
        if (t < KT - 1) STAGE(wsl, t + 1);

        // ---- 32 MFMA, one cluster ----
        __builtin_amdgcn_s_setprio(1);
#pragma unroll
        for (int m = 0; m < 4; ++m)
#pragma unroll
            for (int n = 0; n < 4; ++n) {
                acc[m][n] = __builtin_amdgcn_mfma_f32_16x16x32_bf16(
                    aA[m][0], bB[n][0], acc[m][n], 0, 0, 0);
                acc[m][n] = __builtin_amdgcn_mfma_f32_16x16x32_bf16(
                    aA[m][1], bB[n][1], acc[m][n], 0, 0, 0);
            }
        __builtin_amdgcn_s_setprio(0);

        if (t < KT - 1) {
            asm volatile("s_waitcnt vmcnt(0)" ::: "memory");
            __builtin_amdgcn_s_barrier();
        }
    }

    // ---- epilogue: +b2, *mask (R1-proven 16x16 mapping) ----
#pragma unroll
    for (int m = 0; m < 4; ++m) {
        int rbase = row0 + wr * 64 + m * 16 + fk * 4;
#pragma unroll
        for (int j = 0; j < 4; ++j) {
            int r = rbase + j;
            float mk = mask[r];
#pragma unroll
            for (int n = 0; n < 4; ++n) {
                int c = col0 + wc * 64 + n * 16 + frow;
                C[(size_t)r * N + c] = (acc[m][n][j] + b2[c]) * mk;
            }
        }
    }
}

extern "C" void kernel_launch(void* const* d_in, const int* in_sizes, int n_in,
                              void* d_out, int out_size, void* d_ws, size_t ws_size,
                              hipStream_t stream) {
    const int* etype   = (const int*)d_in[0];
    const float* conf  = (const float*)d_in[1];
    const float* loc   = (const float*)d_in[2];
    const int* bidx    = (const int*)d_in[3];
    const float* emb   = (const float*)d_in[5];
    const float* W1    = (const float*)d_in[6];
    const float* b1    = (const float*)d_in[7];
    const float* W2    = (const float*)d_in[8];
    const float* b2    = (const float*)d_in[9];
    float* out = (float*)d_out;

    int E  = in_sizes[0];
    int d2 = in_sizes[7];           // 2048
    int d  = in_sizes[9];           // 4096
    int d4 = in_sizes[5] / NT;      // 1024
    int B  = out_size / d;          // 16384

    char* ws = (char*)d_ws;
    unsigned long long* packed = (unsigned long long*)ws;     // B*8
    float* mask = (float*)(ws + (size_t)B * 8);               // B*4
    float* base = mask + B;                                   // NT*d2
    float* vecs = base + NT * d2;                             // 3*d2
    short* w2b  = (short*)(vecs + 3 * d2);                    // d*d2 bf16
    short* h    = w2b + (size_t)d * d2;                       // B*d2 bf16

    hipMemsetAsync(packed, 0, (size_t)B * 8, stream);
    k_segmax<<<(E + 255) / 256, 256, 0, stream>>>(conf, bidx, packed, E);
    k_base<<<(NT * d2) / 4, 256, 0, stream>>>(emb, W1, b1, base, vecs, d2, d4);
    long nw2 = (long)d * d2;
    k_w2cast<<<(int)(nw2 / 8 / 256), 256, 0, stream>>>(W2, w2b, nw2);
    k_h<<<B, 256, 0, stream>>>(packed, etype, loc, base, vecs, mask, h, d2);
    int nbm = B / BM, nbn = d / BN;
    k_gemm<<<dim3(nbm * nbn), dim3(256), 0, stream>>>(h, w2b, b2, mask, out, B, d, d2, nbn);
}

// Round 16
// 330.931 us; speedup vs baseline: 1.4182x; 1.0517x over previous
//
#include <hip/hip_runtime.h>
#include <hip/hip_bf16.h>

#define NT 6
#define BM 256
#define BN 256
#define BK 64
#define SLOT_S 32768      // shorts per dbuf slot: A 256x64 + B 256x64 = 64KB
#define AH1 8192          // A rows 128-255 (shorts)
#define BOFF_A 16384      // B base within slot (shorts)
#define BH1 24576

typedef __attribute__((ext_vector_type(16))) float f32x16;
typedef __attribute__((ext_vector_type(8))) short bf16x8;

__device__ __forceinline__ short f2bf(float f) {
    __hip_bfloat16 h = __float2bfloat16(f);
    return (short)__builtin_bit_cast(unsigned short, h);
}

// ---- 1. segment argmax: packed (conf_bits<<32) | ~idx, atomicMax ----
__global__ void k_segmax(const float* __restrict__ conf,
                         const int* __restrict__ bidx,
                         unsigned long long* __restrict__ packed, int E) {
    int i = blockIdx.x * blockDim.x + threadIdx.x;
    if (i >= E) return;
    unsigned cb = __float_as_uint(conf[i]);
    unsigned long long p = ((unsigned long long)cb << 32) | (unsigned)(~(unsigned)i);
    atomicMax(&packed[bidx[i]], p);
}

// ---- 2. base[t][n] = emb[t] . W1[n,:d4] + b1[n]; extract conf/x/y columns ----
__global__ void k_base(const float* __restrict__ emb, const float* __restrict__ W1,
                       const float* __restrict__ b1, float* __restrict__ base,
                       float* __restrict__ vecs, int d2, int d4) {
    int gw = (blockIdx.x * blockDim.x + threadIdx.x) >> 6;
    int lane = threadIdx.x & 63;
    int t = gw / d2, n = gw % d2;
    const float* e = emb + (size_t)t * d4;
    const float* w = W1 + (size_t)n * (d4 + 3);
    float s = 0.f;
    for (int k = lane; k < d4; k += 64) s += e[k] * w[k];
#pragma unroll
    for (int m = 32; m; m >>= 1) s += __shfl_xor(s, m);
    if (lane == 0) {
        base[gw] = s + b1[n];
        if (t == 0) {
            vecs[n]          = w[d4];
            vecs[d2 + n]     = w[d4 + 1];
            vecs[2 * d2 + n] = w[d4 + 2];
        }
    }
}

// ---- 3. W2 fp32 -> bf16 ----
__global__ void k_w2cast(const float* __restrict__ W2, short* __restrict__ W2b, long n) {
    long i = ((long)blockIdx.x * blockDim.x + threadIdx.x) * 8;
    if (i >= n) return;
    bf16x8 v;
#pragma unroll
    for (int j = 0; j < 8; ++j) v[j] = f2bf(W2[i + j]);
    *(bf16x8*)(W2b + i) = v;
}

// ---- 4. h[b][n] = relu(base[t][n] + conf*cv[n] + lx*xv[n] + ly*yv[n]) -> bf16 ----
__global__ void k_h(const unsigned long long* __restrict__ packed,
                    const int* __restrict__ etype, const float* __restrict__ loc,
                    const float* __restrict__ base, const float* __restrict__ vecs,
                    float* __restrict__ mask, short* __restrict__ h, int d2) {
    int b = blockIdx.x;
    int tid = threadIdx.x;
    unsigned long long p = packed[b];
    bool has = (p != 0ULL);
    float conf = 0.f, lx = 0.f, ly = 0.f;
    int t = 0;
    if (has) {
        unsigned idx = ~(unsigned)(p & 0xFFFFFFFFu);
        conf = __uint_as_float((unsigned)(p >> 32));
        t  = etype[idx];
        lx = loc[2 * (size_t)idx]     * (1.0f / 640.0f);
        ly = loc[2 * (size_t)idx + 1] * (1.0f / 480.0f);
    }
    if (tid == 0) mask[b] = has ? 1.0f : 0.0f;
    const float* bs = base + (size_t)t * d2;
    const float* cv = vecs;
    const float* xv = vecs + d2;
    const float* yv = vecs + 2 * d2;
    int n0 = tid * 8;
    bf16x8 v;
#pragma unroll
    for (int j = 0; j < 8; ++j) {
        int n = n0 + j;
        float g = bs[n] + conf * cv[n] + lx * xv[n] + ly * yv[n];
        g = fmaxf(g, 0.f);
        v[j] = has ? f2bf(g) : (short)0;
    }
    *(bf16x8*)(h + (size_t)b * d2 + n0) = v;
}

// ---- 5. GEMM: R10 mega-phase + 32x32x16 MFMA ----
// 256x256, BK=64, 2-slot dbuf (128 KiB), 8 waves (2x4), wave tile 128x64
// decomposed as 4 m-tiles x 2 n-tiles of 32x32.
// Per K64 tile: {24 ds_read_b128 (16 A + 8 B frags); 8 GLL staging t+1;
// 32 MFMA_32x32x16 one cluster; vmcnt(0); barrier} — R10's proven deep-
// queue structure, MFMA pipe 2484 -> ~2066 cyc (2495 vs 2075 TF ceiling).
// Conflict analysis at this geometry (128B rows -> all rows bank-aligned;
// swizzle: phys chunk p of row r holds global chunk p^(r&7)): 32x32 frag
// read phys = (2s+kh)^(l&7); every 16-lane quarter spans all 8 chunks
// exactly 2x -> 2-way, free (m136). (R5's conflicts were an artifact of
// the 64B-row/(r>>1)&3 geometry, absent here.)
// Epilogue mapping: col=lane&31, row=(reg&3)+8*(reg>>2)+4*(lane>>5) —
// R5-verified end-to-end (passed absmax).

#define GLL(src, dst) __builtin_amdgcn_global_load_lds(                      \
    (const __attribute__((address_space(1))) void*)(src),                    \
    (__attribute__((address_space(3))) void*)(dst), 16, 0, 0)

#define ST_AH0(ws, kt) { GLL(pA + (size_t)(kt) * 64, (ws) + dst1);           \
                         GLL(pA + (size_t)64 * K + (kt) * 64, (ws) + dst2); }
#define ST_AH1(ws, kt) { GLL(pA + (size_t)128 * K + (kt) * 64, (ws) + AH1 + dst1); \
                         GLL(pA + (size_t)192 * K + (kt) * 64, (ws) + AH1 + dst2); }
#define ST_BH0(ws, kt) { GLL(pB + (size_t)(kt) * 64, (ws) + BOFF_A + dst1);  \
                         GLL(pB + (size_t)64 * K + (kt) * 64, (ws) + BOFF_A + dst2); }
#define ST_BH1(ws, kt) { GLL(pB + (size_t)128 * K + (kt) * 64, (ws) + BH1 + dst1); \
                         GLL(pB + (size_t)192 * K + (kt) * 64, (ws) + BH1 + dst2); }

__global__ __launch_bounds__(512, 2)
void k_gemm(const short* __restrict__ A, const short* __restrict__ Bm,
            const float* __restrict__ b2, const float* __restrict__ mask,
            float* __restrict__ C, int M, int N, int K, int nbn) {
    __shared__ __align__(16) short lds[2 * SLOT_S];   // 128 KiB

    int tid = threadIdx.x;
    int lane = tid & 63;
    int wave = tid >> 6;            // 0..7
    int wr = wave >> 2, wc = wave & 3;

    // XCD-aware bijective swizzle (grid = 1024, % 8 == 0)
    int bid = blockIdx.x;
    int wg = (bid & 7) * ((int)gridDim.x >> 3) + (bid >> 3);
    int bm = wg / nbn, bn = wg % nbn;
    int row0 = bm * BM, col0 = bn * BN;

    // ---- staging precompute (R10-verified) ----
    int r1 = tid >> 3;                         // 0..63
    int pg = tid & 7;
    int cg = pg ^ (r1 & 7);                    // inverse-swizzled source chunk
    const short* pA = A + (size_t)(row0 + r1) * K + cg * 8;
    const short* pB = Bm + (size_t)(col0 + r1) * K + cg * 8;
    int dst1 = tid * 8;
    int dst2 = 4096 + tid * 8;

    // ---- 32x32 fragment read offsets ----
    int l31 = lane & 31, kh = lane >> 5;       // row/col in tile, k-half
    int kx7 = l31 & 7;
    int aBase = (wr * 128 + l31) * 64;         // + mi*2048
    int bBase = BOFF_A + (wc * 64 + l31) * 64; // + ni*2048
    int coff[4];
#pragma unroll
    for (int s = 0; s < 4; ++s) coff[s] = ((2 * s + kh) ^ kx7) * 8;

    f32x16 acc[4][2] = {};
    bf16x8 aA[4][4], bB[2][4];

    int KT = K / BK;                           // 32

    // ---- prologue: stage tile 0 into slot 0, drain once ----
    ST_AH0(lds, 0); ST_BH0(lds, 0); ST_BH1(lds, 0); ST_AH1(lds, 0);
    asm volatile("s_waitcnt vmcnt(0)" ::: "memory");
    __builtin_amdgcn_s_barrier();

#pragma unroll 1
    for (int t = 0; t < KT; ++t) {
        const short* sl = lds + (t & 1) * SLOT_S;
        short* wsl = lds + ((t + 1) & 1) * SLOT_S;

        // ---- 24 ds_read_b128: whole tile's fragments ----
#pragma unroll
        for (int mi = 0; mi < 4; ++mi)
#pragma unroll
            for (int s = 0; s < 4; ++s)
                aA[mi][s] = *(const bf16x8*)(sl + aBase + mi * 2048 + coff[s]);
#pragma unroll
        for (int ni = 0; ni < 2; ++ni)
#pragma unroll
            for (int s = 0; s < 4; ++s)
                bB[ni][s] = *(const bf16x8*)(sl + bBase + ni * 2048 + coff[s]);

        // ---- stage tile t+1 (8 GLL) — lands under the MFMA cluster ----
        if (t < KT - 1) {
            ST_AH0(wsl, t + 1); ST_BH0(wsl, t + 1);
            ST_BH1(wsl, t + 1); ST_AH1(wsl, t + 1);
        }

        // ---- 32 MFMA 32x32x16, one cluster ----
        __builtin_amdgcn_s_setprio(1);
#pragma unroll
        for (int mi = 0; mi < 4; ++mi)
#pragma unroll
            for (int ni = 0; ni < 2; ++ni)
#pragma unroll
                for (int s = 0; s < 4; ++s)
                    acc[mi][ni] = __builtin_amdgcn_mfma_f32_32x32x16_bf16(
                        aA[mi][s], bB[ni][s], acc[mi][ni], 0, 0, 0);
        __builtin_amdgcn_s_setprio(0);

        if (t < KT - 1) {
            asm volatile("s_waitcnt vmcnt(0)" ::: "memory");
            __builtin_amdgcn_s_barrier();
        }
    }

    // ---- epilogue: +b2, *mask (R5-verified 32x32 C/D mapping) ----
#pragma unroll
    for (int mi = 0; mi < 4; ++mi) {
        int rb = row0 + wr * 128 + mi * 32 + 4 * kh;
#pragma unroll
        for (int q = 0; q < 4; ++q) {
#pragma unroll
            for (int j = 0; j < 4; ++j) {
                int r = rb + 8 * q + j;
                float mk = mask[r];
#pragma unroll
                for (int ni = 0; ni < 2; ++ni) {
                    int c = col0 + wc * 64 + ni * 32 + l31;
                    C[(size_t)r * N + c] = (acc[mi][ni][q * 4 + j] + b2[c]) * mk;
                }
            }
        }
    }
}

extern "C" void kernel_launch(void* const* d_in, const int* in_sizes, int n_in,
                              void* d_out, int out_size, void* d_ws, size_t ws_size,
                              hipStream_t stream) {
    const int* etype   = (const int*)d_in[0];
    const float* conf  = (const float*)d_in[1];
    const float* loc   = (const float*)d_in[2];
    const int* bidx    = (const int*)d_in[3];
    const float* emb   = (const float*)d_in[5];
    const float* W1    = (const float*)d_in[6];
    const float* b1    = (const float*)d_in[7];
    const float* W2    = (const float*)d_in[8];
    const float* b2    = (const float*)d_in[9];
    float* out = (float*)d_out;

    int E  = in_sizes[0];
    int d2 = in_sizes[7];           // 2048
    int d  = in_sizes[9];           // 4096
    int d4 = in_sizes[5] / NT;      // 1024
    int B  = out_size / d;          // 16384

    char* ws = (char*)d_ws;
    unsigned long long* packed = (unsigned long long*)ws;     // B*8
    float* mask = (float*)(ws + (size_t)B * 8);               // B*4
    float* base = mask + B;                                   // NT*d2
    float* vecs = base + NT * d2;                             // 3*d2
    short* w2b  = (short*)(vecs + 3 * d2);                    // d*d2 bf16
    short* h    = w2b + (size_t)d * d2;                       // B*d2 bf16

    hipMemsetAsync(packed, 0, (size_t)B * 8, stream);
    k_segmax<<<(E + 255) / 256, 256, 0, stream>>>(conf, bidx, packed, E);
    k_base<<<(NT * d2) / 4, 256, 0, stream>>>(emb, W1, b1, base, vecs, d2, d4);
    long nw2 = (long)d * d2;
    k_w2cast<<<(int)(nw2 / 8 / 256), 256, 0, stream>>>(W2, w2b, nw2);
    k_h<<<B, 256, 0, stream>>>(packed, etype, loc, base, vecs, mask, h, d2);
    int nbm = B / BM, nbn = d / BN;
    k_gemm<<<dim3(nbm * nbn), dim3(512), 0, stream>>>(h, w2b, b2, mask, out, B, d, d2, nbn);
}

// Round 17
// 297.524 us; speedup vs baseline: 1.5775x; 1.1123x over previous
//
#include <hip/hip_runtime.h>
#include <hip/hip_bf16.h>

#define NT 6
#define BM 256
#define BN 256
#define BK 64
#define SLOT_S 32768      // shorts per dbuf slot: (A 256x64 + B 256x64) = 64KB
// slot layout (shorts): A-h0 @0 (rows 0-127), A-h1 @8192 (rows 128-255),
//                       B-h0 @16384, B-h1 @24576
#define AH1 8192
#define BH0 16384
#define BH1 24576

typedef __attribute__((ext_vector_type(4))) float f32x4;
typedef __attribute__((ext_vector_type(8))) short bf16x8;

__device__ __forceinline__ short f2bf(float f) {
    __hip_bfloat16 h = __float2bfloat16(f);
    return (short)__builtin_bit_cast(unsigned short, h);
}

// ---- 1. segment argmax: packed (conf_bits<<32) | ~idx, atomicMax ----
__global__ void k_segmax(const float* __restrict__ conf,
                         const int* __restrict__ bidx,
                         unsigned long long* __restrict__ packed, int E) {
    int i = blockIdx.x * blockDim.x + threadIdx.x;
    if (i >= E) return;
    unsigned cb = __float_as_uint(conf[i]);
    unsigned long long p = ((unsigned long long)cb << 32) | (unsigned)(~(unsigned)i);
    atomicMax(&packed[bidx[i]], p);
}

// ---- 2. base[t][n] = emb[t] . W1[n,:d4] + b1[n]; extract conf/x/y columns ----
__global__ void k_base(const float* __restrict__ emb, const float* __restrict__ W1,
                       const float* __restrict__ b1, float* __restrict__ base,
                       float* __restrict__ vecs, int d2, int d4) {
    int gw = (blockIdx.x * blockDim.x + threadIdx.x) >> 6;
    int lane = threadIdx.x & 63;
    int t = gw / d2, n = gw % d2;
    const float* e = emb + (size_t)t * d4;
    const float* w = W1 + (size_t)n * (d4 + 3);
    float s = 0.f;
    for (int k = lane; k < d4; k += 64) s += e[k] * w[k];
#pragma unroll
    for (int m = 32; m; m >>= 1) s += __shfl_xor(s, m);
    if (lane == 0) {
        base[gw] = s + b1[n];
        if (t == 0) {
            vecs[n]          = w[d4];
            vecs[d2 + n]     = w[d4 + 1];
            vecs[2 * d2 + n] = w[d4 + 2];
        }
    }
}

// ---- 3. W2 fp32 -> bf16 ----
__global__ void k_w2cast(const float* __restrict__ W2, short* __restrict__ W2b, long n) {
    long i = ((long)blockIdx.x * blockDim.x + threadIdx.x) * 8;
    if (i >= n) return;
    bf16x8 v;
#pragma unroll
    for (int j = 0; j < 8; ++j) v[j] = f2bf(W2[i + j]);
    *(bf16x8*)(W2b + i) = v;
}

// ---- 4. h[b][n] = relu(base[t][n] + conf*cv[n] + lx*xv[n] + ly*yv[n]) -> bf16 ----
__global__ void k_h(const unsigned long long* __restrict__ packed,
                    const int* __restrict__ etype, const float* __restrict__ loc,
                    const float* __restrict__ base, const float* __restrict__ vecs,
                    float* __restrict__ mask, short* __restrict__ h, int d2) {
    int b = blockIdx.x;
    int tid = threadIdx.x;
    unsigned long long p = packed[b];
    bool has = (p != 0ULL);
    float conf = 0.f, lx = 0.f, ly = 0.f;
    int t = 0;
    if (has) {
        unsigned idx = ~(unsigned)(p & 0xFFFFFFFFu);
        conf = __uint_as_float((unsigned)(p >> 32));
        t  = etype[idx];
        lx = loc[2 * (size_t)idx]     * (1.0f / 640.0f);
        ly = loc[2 * (size_t)idx + 1] * (1.0f / 480.0f);
    }
    if (tid == 0) mask[b] = has ? 1.0f : 0.0f;
    const float* bs = base + (size_t)t * d2;
    const float* cv = vecs;
    const float* xv = vecs + d2;
    const float* yv = vecs + 2 * d2;
    int n0 = tid * 8;
    bf16x8 v;
#pragma unroll
    for (int j = 0; j < 8; ++j) {
        int n = n0 + j;
        float g = bs[n] + conf * cv[n] + lx * xv[n] + ly * yv[n];
        g = fmaxf(g, 0.f);
        v[j] = has ? f2bf(g) : (short)0;
    }
    *(bf16x8*)(h + (size_t)b * d2 + n0) = v;
}

// ---- 5. GEMM: single-mega-phase per K64 tile (R10 champion, restored) ----
// 256x256, BK=64, 2-slot dbuf (128 KiB), 8 waves (2x4), 16x16x32 MFMA.
// Per K64 tile: {24 ds_read_b128 (whole tile's frags); 8 GLL staging t+1;
// 64 MFMA in ONE cluster (compiler interleaves counted lgkm waits);
// vmcnt(0); barrier}. The deep read queue ahead of the long MFMA cluster
// is the proven lever (R10: 263us vs 280-310 for all phase-split variants).
// setprio REMOVED: single-phase lockstep = T5's null/negative regime (m190).
// Swizzle (verified 0-conflict): LDS phys chunk p of row r holds global
// chunk p^(r&7); GLL dest linear, source pre-inverse-swizzled; fragment
// reads apply the same XOR with fk=lane>>4 spanning 4 chunks per quarter
// (the empirically conflict-free pattern; 32x32-style kh-only reads pay
// 4cyc/read — R5/R16).

#define GLL(src, dst) __builtin_amdgcn_global_load_lds(                      \
    (const __attribute__((address_space(1))) void*)(src),                    \
    (__attribute__((address_space(3))) void*)(dst), 16, 0, 0)

#define ST_AH0(ws, kt) { GLL(pA + (size_t)(kt) * 64, (ws) + dst1);           \
                         GLL(pA + (size_t)64 * K + (kt) * 64, (ws) + dst2); }
#define ST_AH1(ws, kt) { GLL(pA + (size_t)128 * K + (kt) * 64, (ws) + AH1 + dst1); \
                         GLL(pA + (size_t)192 * K + (kt) * 64, (ws) + AH1 + dst2); }
#define ST_BH0(ws, kt) { GLL(pB + (size_t)(kt) * 64, (ws) + BH0 + dst1);     \
                         GLL(pB + (size_t)64 * K + (kt) * 64, (ws) + BH0 + dst2); }
#define ST_BH1(ws, kt) { GLL(pB + (size_t)128 * K + (kt) * 64, (ws) + BH1 + dst1); \
                         GLL(pB + (size_t)192 * K + (kt) * 64, (ws) + BH1 + dst2); }

__global__ __launch_bounds__(512, 2)
void k_gemm(const short* __restrict__ A, const short* __restrict__ Bm,
            const float* __restrict__ b2, const float* __restrict__ mask,
            float* __restrict__ C, int M, int N, int K, int nbn) {
    __shared__ __align__(16) short lds[2 * SLOT_S];   // 128 KiB

    int tid = threadIdx.x;
    int lane = tid & 63;
    int wave = tid >> 6;            // 0..7
    int wr = wave >> 2, wc = wave & 3;

    // XCD-aware bijective swizzle (grid = 1024, % 8 == 0)
    int bid = blockIdx.x;
    int wg = (bid & 7) * ((int)gridDim.x >> 3) + (bid >> 3);
    int bm = wg / nbn, bn = wg % nbn;
    int row0 = bm * BM, col0 = bn * BN;

    // ---- staging precompute (verified) ----
    int r1 = tid >> 3;                         // 0..63
    int pg = tid & 7;
    int cg = pg ^ (r1 & 7);                    // inverse-swizzled source chunk
    const short* pA = A + (size_t)(row0 + r1) * K + cg * 8;
    const short* pB = Bm + (size_t)(col0 + r1) * K + cg * 8;
    int dst1 = tid * 8;
    int dst2 = 4096 + tid * 8;

    // ---- fragment read offsets (verified 0-conflict) ----
    int frow = lane & 15, fk = lane >> 4;
    int kx = frow & 7;
    int aoffs0 = (wr * 64 + frow) * 64 + ((fk) ^ kx) * 8;
    int aoffs1 = (wr * 64 + frow) * 64 + ((4 + fk) ^ kx) * 8;
    int boffs0 = (wc * 32 + frow) * 64 + ((fk) ^ kx) * 8;
    int boffs1 = (wc * 32 + frow) * 64 + ((4 + fk) ^ kx) * 8;

    f32x4 acc[8][4] = {};
    bf16x8 aA[8][2], bB[4][2];

    int KT = K / BK;                           // 32

    // ---- prologue: stage tile 0 into slot 0, drain once ----
    ST_AH0(lds, 0); ST_BH0(lds, 0); ST_BH1(lds, 0); ST_AH1(lds, 0);
    asm volatile("s_waitcnt vmcnt(0)" ::: "memory");
    __builtin_amdgcn_s_barrier();

#pragma unroll 1
    for (int t = 0; t < KT; ++t) {
        const short* sl = lds + (t & 1) * SLOT_S;
        short* wsl = lds + ((t + 1) & 1) * SLOT_S;

        // ---- 24 ds_read_b128: whole tile's fragments to registers ----
#pragma unroll
        for (int m = 0; m < 4; ++m) {
            aA[m][0]     = *(const bf16x8*)(sl + aoffs0 + m * 1024);
            aA[m][1]     = *(const bf16x8*)(sl + aoffs1 + m * 1024);
        }
#pragma unroll
        for (int n = 0; n < 2; ++n) {
            bB[n][0]     = *(const bf16x8*)(sl + BH0 + boffs0 + n * 1024);
            bB[n][1]     = *(const bf16x8*)(sl + BH0 + boffs1 + n * 1024);
            bB[2 + n][0] = *(const bf16x8*)(sl + BH1 + boffs0 + n * 1024);
            bB[2 + n][1] = *(const bf16x8*)(sl + BH1 + boffs1 + n * 1024);
        }
#pragma unroll
        for (int m = 0; m < 4; ++m) {
            aA[4 + m][0] = *(const bf16x8*)(sl + AH1 + aoffs0 + m * 1024);
            aA[4 + m][1] = *(const bf16x8*)(sl + AH1 + aoffs1 + m * 1024);
        }

        // ---- stage tile t+1 (8 GLL) — lands under the MFMA cluster ----
        if (t < KT - 1) {
            ST_AH0(wsl, t + 1); ST_BH0(wsl, t + 1);
            ST_BH1(wsl, t + 1); ST_AH1(wsl, t + 1);
        }

        // ---- 64 MFMA, one cluster ----
#pragma unroll
        for (int m = 0; m < 8; ++m)
#pragma unroll
            for (int n = 0; n < 4; ++n) {
                acc[m][n] = __builtin_amdgcn_mfma_f32_16x16x32_bf16(
                    aA[m][0], bB[n][0], acc[m][n], 0, 0, 0);
                acc[m][n] = __builtin_amdgcn_mfma_f32_16x16x32_bf16(
                    aA[m][1], bB[n][1], acc[m][n], 0, 0, 0);
            }

        if (t < KT - 1) {
            asm volatile("s_waitcnt vmcnt(0)" ::: "memory");
            __builtin_amdgcn_s_barrier();
        }
    }

    // ---- epilogue: +b2, *mask (verified mapping) ----
#pragma unroll
    for (int mi = 0; mi < 8; ++mi) {
        int rbase = row0 + (mi >> 2) * 128 + wr * 64 + (mi & 3) * 16 + fk * 4;
#pragma unroll
        for (int j = 0; j < 4; ++j) {
            int r = rbase + j;
            float mk = mask[r];
#pragma unroll
            for (int ni = 0; ni < 4; ++ni) {
                int cc = col0 + (ni >> 1) * 128 + wc * 32 + (ni & 1) * 16 + frow;
                C[(size_t)r * N + cc] = (acc[mi][ni][j] + b2[cc]) * mk;
            }
        }
    }
}

extern "C" void kernel_launch(void* const* d_in, const int* in_sizes, int n_in,
                              void* d_out, int out_size, void* d_ws, size_t ws_size,
                              hipStream_t stream) {
    const int* etype   = (const int*)d_in[0];
    const float* conf  = (const float*)d_in[1];
    const float* loc   = (const float*)d_in[2];
    const int* bidx    = (const int*)d_in[3];
    const float* emb   = (const float*)d_in[5];
    const float* W1    = (const float*)d_in[6];
    const float* b1    = (const float*)d_in[7];
    const float* W2    = (const float*)d_in[8];
    const float* b2    = (const float*)d_in[9];
    float* out = (float*)d_out;

    int E  = in_sizes[0];
    int d2 = in_sizes[7];           // 2048
    int d  = in_sizes[9];           // 4096
    int d4 = in_sizes[5] / NT;      // 1024
    int B  = out_size / d;          // 16384

    char* ws = (char*)d_ws;
    unsigned long long* packed = (unsigned long long*)ws;     // B*8
    float* mask = (float*)(ws + (size_t)B * 8);               // B*4
    float* base = mask + B;                                   // NT*d2
    float* vecs = base + NT * d2;                             // 3*d2
    short* w2b  = (short*)(vecs + 3 * d2);                    // d*d2 bf16
    short* h    = w2b + (size_t)d * d2;                       // B*d2 bf16

    hipMemsetAsync(packed, 0, (size_t)B * 8, stream);
    k_segmax<<<(E + 255) / 256, 256, 0, stream>>>(conf, bidx, packed, E);
    k_base<<<(NT * d2) / 4, 256, 0, stream>>>(emb, W1, b1, base, vecs, d2, d4);
    long nw2 = (long)d * d2;
    k_w2cast<<<(int)(nw2 / 8 / 256), 256, 0, stream>>>(W2, w2b, nw2);
    k_h<<<B, 256, 0, stream>>>(packed, etype, loc, base, vecs, mask, h, d2);
    int nbm = B / BM, nbn = d / BN;
    k_gemm<<<dim3(nbm * nbn), dim3(512), 0, stream>>>(h, w2b, b2, mask, out, B, d, d2, nbn);
}